// Round 1
// baseline (1138.465 us; speedup 1.0000x reference)
//
#include <hip/hip_runtime.h>
#include <hip/hip_bf16.h>

// Problem constants (from reference): B,T,M,D,DOUT = 2,10000,100000,128,128
#define BB    2
#define TT    10000
#define MM    100000
#define DD    128
#define DOUTN 128
#define NROWS (BB * TT * 2)     // 40000 rows of X / out
#define NTILES (NROWS / 16)     // 2500 MFMA row-tiles

typedef float  f32x4  __attribute__((ext_vector_type(4)));
typedef short  bf16x8 __attribute__((ext_vector_type(8)));

static __device__ __forceinline__ short f2bf(float f) {
    union { float f; unsigned u; } v; v.f = f;
    unsigned r = v.u + 0x7fffu + ((v.u >> 16) & 1u);   // RNE
    return (short)(r >> 16);
}

// Kernel 1: y = X * W^T (no bias) into ws; out = y + bias.
// One wave per 16-row tile. A-frags from global (8 consecutive fp32/lane),
// all 32 B-frags (8 o-tiles x 4 k-steps) hoisted to VGPRs once per wave.
__global__ __launch_bounds__(256, 2)
void gemm_y_kernel(const float* __restrict__ X, const float* __restrict__ W,
                   const float* __restrict__ bias,
                   float* __restrict__ y, float* __restrict__ out) {
    const int lane = threadIdx.x & 63;
    const int wid  = threadIdx.x >> 6;
    const int l15  = lane & 15;
    const int q    = lane >> 4;          // 0..3

    // Hoist W fragments. B[k][n] = W[ot*16 + n][k]; lane holds n=l15,
    // k = s*32 + q*8 + j.
    bf16x8 bf[8][4];
#pragma unroll
    for (int ot = 0; ot < 8; ++ot) {
        const float* wp = W + (ot * 16 + l15) * DD + q * 8;
#pragma unroll
        for (int s = 0; s < 4; ++s) {
            float4 w0 = *(const float4*)(wp + s * 32);
            float4 w1 = *(const float4*)(wp + s * 32 + 4);
            bf16x8 t;
            t[0] = f2bf(w0.x); t[1] = f2bf(w0.y); t[2] = f2bf(w0.z); t[3] = f2bf(w0.w);
            t[4] = f2bf(w1.x); t[5] = f2bf(w1.y); t[6] = f2bf(w1.z); t[7] = f2bf(w1.w);
            bf[ot][s] = t;
        }
    }
    float bias_v[8];
#pragma unroll
    for (int ot = 0; ot < 8; ++ot) bias_v[ot] = bias[ot * 16 + l15];

    const int tile = blockIdx.x * 4 + wid;
    if (tile >= NTILES) return;

    // A[m][k]: lane holds m = l15 (row tile*16+l15), k = s*32 + q*8 + j
    const float* xp = X + (tile * 16 + l15) * DD + q * 8;

    f32x4 acc[8];
#pragma unroll
    for (int ot = 0; ot < 8; ++ot) acc[ot] = (f32x4){0.f, 0.f, 0.f, 0.f};

#pragma unroll
    for (int s = 0; s < 4; ++s) {
        float4 a0 = *(const float4*)(xp + s * 32);
        float4 a1 = *(const float4*)(xp + s * 32 + 4);
        bf16x8 a;
        a[0] = f2bf(a0.x); a[1] = f2bf(a0.y); a[2] = f2bf(a0.z); a[3] = f2bf(a0.w);
        a[4] = f2bf(a1.x); a[5] = f2bf(a1.y); a[6] = f2bf(a1.z); a[7] = f2bf(a1.w);
#pragma unroll
        for (int ot = 0; ot < 8; ++ot)
            acc[ot] = __builtin_amdgcn_mfma_f32_16x16x32_bf16(a, bf[ot][s], acc[ot], 0, 0, 0);
    }

    // D layout: col = l15 (+16*ot), row = tile*16 + q*4 + r
#pragma unroll
    for (int ot = 0; ot < 8; ++ot) {
        const int col = ot * 16 + l15;
#pragma unroll
        for (int r = 0; r < 4; ++r) {
            const int row = tile * 16 + q * 4 + r;
            const float v = acc[ot][r];
            y[row * DOUTN + col]   = v;
            out[row * DOUTN + col] = v + bias_v[ot];
        }
    }
}

// Kernel 2: out[b, in_m, c, :] += A[b,m] * y[b, out_m, c, :]
// Thread = (edge-row, float4 quad). 32 consecutive threads cover one 512B row.
__global__ __launch_bounds__(256)
void scatter_add_kernel(const float* __restrict__ y, const int* __restrict__ edge,
                        const float* __restrict__ Am, float* __restrict__ out) {
    const int tid = blockIdx.x * 256 + threadIdx.x;
    const int q   = tid & 31;          // float4 index within row
    const int row = tid >> 5;          // 0 .. 4*MM-1
    if (row >= 4 * MM) return;
    const int m  = row >> 2;
    const int bc = row & 3;
    const int b  = bc >> 1;
    const int c  = bc & 1;

    const int nin  = edge[m];          // edge[0][m] = node_in
    const int nout = edge[MM + m];     // edge[1][m] = node_out
    const float w  = Am[b * MM + m];

    const float4 v = *((const float4*)(y + (((b * TT + nout) * 2 + c) * DD)) + q);
    float* dst = out + (((b * TT + nin) * 2 + c) * DD) + q * 4;
    atomicAdd(dst + 0, v.x * w);
    atomicAdd(dst + 1, v.y * w);
    atomicAdd(dst + 2, v.z * w);
    atomicAdd(dst + 3, v.w * w);
}

extern "C" void kernel_launch(void* const* d_in, const int* in_sizes, int n_in,
                              void* d_out, int out_size, void* d_ws, size_t ws_size,
                              hipStream_t stream) {
    const float* x1   = (const float*)d_in[0];   // (B,T,2,D)
    // d_in[1] = x_2nd, unused by the reference
    const int*   edge = (const int*)d_in[2];     // (2,M)
    const float* Am   = (const float*)d_in[3];   // (B,1,M)
    const float* W    = (const float*)d_in[4];   // (DOUT,D)
    const float* bias = (const float*)d_in[5];   // (DOUT,)
    float* out = (float*)d_out;                  // (B,T,2,DOUT)
    float* y   = (float*)d_ws;                   // NROWS*DOUTN fp32 = 20.5 MB

    gemm_y_kernel<<<(NTILES + 3) / 4, 256, 0, stream>>>(x1, W, bias, y, out);

    const int scatter_threads = 4 * MM * 32;     // 12.8M
    scatter_add_kernel<<<(scatter_threads + 255) / 256, 256, 0, stream>>>(y, edge, Am, out);
}

// Round 2
// 561.770 us; speedup vs baseline: 2.0266x; 2.0266x over previous
//
#include <hip/hip_runtime.h>
#include <hip/hip_bf16.h>

// Problem constants (from reference): B,T,M,D,DOUT = 2,10000,100000,128,128
#define BB    2
#define TT    10000
#define MM    100000
#define DD    128
#define DOUTN 128
#define NROWS (BB * TT * 2)     // 40000 rows of X / y / out
#define NTILES (NROWS / 16)     // 2500 MFMA row-tiles

typedef float  f32x4  __attribute__((ext_vector_type(4)));
typedef short  bf16x8 __attribute__((ext_vector_type(8)));

static __device__ __forceinline__ short f2bf(float f) {
    union { float f; unsigned u; } v; v.f = f;
    unsigned r = v.u + 0x7fffu + ((v.u >> 16) & 1u);   // RNE
    return (short)(r >> 16);
}

// ---------------------------------------------------------------------------
// GEMM: y = X * W^T (no bias). One wave per 16-row x 64-col tile -> 5000 waves.
// A-frags straight from global (8 consecutive fp32/lane matches A layout);
// 16 W B-frags (4 col-tiles x 4 k-steps) hoisted to VGPRs (64 regs).
// ---------------------------------------------------------------------------
__global__ __launch_bounds__(256)
void gemm_y_kernel(const float* __restrict__ X, const float* __restrict__ W,
                   float* __restrict__ y) {
    const int lane = threadIdx.x & 63;
    const int wid  = threadIdx.x >> 6;
    const int l15  = lane & 15;
    const int q    = lane >> 4;          // 0..3

    const int gw   = blockIdx.x * 4 + wid;   // 0..4999
    const int tile = gw >> 1;
    const int half = gw & 1;                 // which 64-col half
    if (tile >= NTILES) return;

    // B[k][n] = W[half*64 + ot*16 + n][k]; lane holds n=l15, k = s*32 + q*8 + j
    bf16x8 bfrag[4][4];
#pragma unroll
    for (int ot = 0; ot < 4; ++ot) {
        const float* wp = W + (half * 64 + ot * 16 + l15) * DD + q * 8;
#pragma unroll
        for (int s = 0; s < 4; ++s) {
            float4 w0 = *(const float4*)(wp + s * 32);
            float4 w1 = *(const float4*)(wp + s * 32 + 4);
            bf16x8 t;
            t[0] = f2bf(w0.x); t[1] = f2bf(w0.y); t[2] = f2bf(w0.z); t[3] = f2bf(w0.w);
            t[4] = f2bf(w1.x); t[5] = f2bf(w1.y); t[6] = f2bf(w1.z); t[7] = f2bf(w1.w);
            bfrag[ot][s] = t;
        }
    }

    // A[m][k]: lane holds m = l15 (row tile*16+l15), k = s*32 + q*8 + j
    const float* xp = X + (tile * 16 + l15) * DD + q * 8;

    f32x4 acc[4];
#pragma unroll
    for (int ot = 0; ot < 4; ++ot) acc[ot] = (f32x4){0.f, 0.f, 0.f, 0.f};

#pragma unroll
    for (int s = 0; s < 4; ++s) {
        float4 a0 = *(const float4*)(xp + s * 32);
        float4 a1 = *(const float4*)(xp + s * 32 + 4);
        bf16x8 a;
        a[0] = f2bf(a0.x); a[1] = f2bf(a0.y); a[2] = f2bf(a0.z); a[3] = f2bf(a0.w);
        a[4] = f2bf(a1.x); a[5] = f2bf(a1.y); a[6] = f2bf(a1.z); a[7] = f2bf(a1.w);
#pragma unroll
        for (int ot = 0; ot < 4; ++ot)
            acc[ot] = __builtin_amdgcn_mfma_f32_16x16x32_bf16(a, bfrag[ot][s], acc[ot], 0, 0, 0);
    }

    // D layout: col = half*64 + ot*16 + l15, row = tile*16 + q*4 + r
#pragma unroll
    for (int ot = 0; ot < 4; ++ot) {
        const int col = half * 64 + ot * 16 + l15;
#pragma unroll
        for (int r = 0; r < 4; ++r) {
            const int row = tile * 16 + q * 4 + r;
            y[row * DOUTN + col] = acc[ot][r];
        }
    }
}

// ---------------------------------------------------------------------------
// CSR build: cnt -> scan -> fill. cur[] is count, then cursor, then bucket-end.
// ---------------------------------------------------------------------------
__global__ __launch_bounds__(256)
void hist_kernel(const int* __restrict__ edge, int* __restrict__ cnt) {
    const int m = blockIdx.x * 256 + threadIdx.x;
    if (m < MM) atomicAdd(&cnt[edge[m]], 1);   // edge[0][m] = node_in = dest
}

#define SCAN_T 1024
#define SCAN_CH 10    // 1024*10 = 10240 >= TT
__global__ __launch_bounds__(SCAN_T)
void scan_kernel(int* __restrict__ cur) {
    __shared__ int sh[SCAN_T];
    const int tid = threadIdx.x;
    int vals[SCAN_CH];
    int sum = 0;
    const int base_i = tid * SCAN_CH;
#pragma unroll
    for (int j = 0; j < SCAN_CH; ++j) {
        const int i = base_i + j;
        const int v = (i < TT) ? cur[i] : 0;
        vals[j] = v; sum += v;
    }
    sh[tid] = sum;
    __syncthreads();
    for (int off = 1; off < SCAN_T; off <<= 1) {
        const int v = (tid >= off) ? sh[tid - off] : 0;
        __syncthreads();
        sh[tid] += v;
        __syncthreads();
    }
    int run = (tid == 0) ? 0 : sh[tid - 1];
#pragma unroll
    for (int j = 0; j < SCAN_CH; ++j) {
        const int i = base_i + j;
        if (i < TT) { cur[i] = run; run += vals[j]; }   // exclusive prefix = cursor start
    }
}

__global__ __launch_bounds__(256)
void fill_kernel(const int* __restrict__ edge, int* __restrict__ cur,
                 int* __restrict__ bucket) {
    const int m = blockIdx.x * 256 + threadIdx.x;
    if (m < MM) {
        const int p = atomicAdd(&cur[edge[m]], 1);
        bucket[p] = m;
    }
    // after this kernel: cur[t] == end of bucket t (inclusive prefix)
}

// ---------------------------------------------------------------------------
// Gather: out[r,:] = y[r,:] + bias + sum_{m: in_m=t} A[b,m] * y[(b,out_m,c),:]
// One wave per row r = (b*TT + t)*2 + c; lane covers 2 floats (float2).
// ---------------------------------------------------------------------------
__global__ __launch_bounds__(256)
void gather_kernel(const float* __restrict__ y, const int* __restrict__ edge,
                   const float* __restrict__ Am, const int* __restrict__ cur_end,
                   const int* __restrict__ bucket, const float* __restrict__ bias,
                   float* __restrict__ out) {
    const int wid  = threadIdx.x >> 6;
    const int lane = threadIdx.x & 63;
    const int r = blockIdx.x * 4 + wid;
    if (r >= NROWS) return;
    const int c = r & 1;
    const int t = (r >> 1) % TT;
    const int b = r / (2 * TT);

    float2 acc = ((const float2*)(y + (size_t)r * DD))[lane];
    const float2 bs = ((const float2*)bias)[lane];

    const int end   = cur_end[t];
    const int start = (t == 0) ? 0 : cur_end[t - 1];
    for (int e = start; e < end; ++e) {
        const int m    = bucket[e];
        const int nout = edge[MM + m];         // edge[1][m] = source
        const float w  = Am[b * MM + m];
        const float2 v = ((const float2*)(y + (size_t)(((b * TT + nout) * 2) + c) * DD))[lane];
        acc.x += w * v.x;
        acc.y += w * v.y;
    }
    float2 o; o.x = acc.x + bs.x; o.y = acc.y + bs.y;
    ((float2*)(out + (size_t)r * DD))[lane] = o;
}

// ---------------------------------------------------------------------------
extern "C" void kernel_launch(void* const* d_in, const int* in_sizes, int n_in,
                              void* d_out, int out_size, void* d_ws, size_t ws_size,
                              hipStream_t stream) {
    const float* x1   = (const float*)d_in[0];   // (B,T,2,D)
    // d_in[1] = x_2nd, unused by the reference
    const int*   edge = (const int*)d_in[2];     // (2,M)
    const float* Am   = (const float*)d_in[3];   // (B,1,M)
    const float* W    = (const float*)d_in[4];   // (DOUT,D)
    const float* bias = (const float*)d_in[5];   // (DOUT,)
    float* out = (float*)d_out;                  // (B,T,2,DOUT)

    // Workspace layout
    float* y      = (float*)d_ws;                          // NROWS*128 fp32 = 20.48 MB
    int*   cur    = (int*)d_ws + (size_t)NROWS * DOUTN;    // TT ints (count->cursor->end)
    int*   bucket = cur + TT;                              // MM ints

    hipMemsetAsync(cur, 0, TT * sizeof(int), stream);
    hist_kernel<<<(MM + 255) / 256, 256, 0, stream>>>(edge, cur);
    scan_kernel<<<1, SCAN_T, 0, stream>>>(cur);
    fill_kernel<<<(MM + 255) / 256, 256, 0, stream>>>(edge, cur, bucket);

    gemm_y_kernel<<<(NTILES * 2 + 3) / 4, 256, 0, stream>>>(x1, W, y);

    gather_kernel<<<(NROWS + 3) / 4, 256, 0, stream>>>(y, edge, Am, cur, bucket, bias, out);
}

// Round 3
// 549.336 us; speedup vs baseline: 2.0724x; 1.0226x over previous
//
#include <hip/hip_runtime.h>
#include <hip/hip_bf16.h>

// Problem constants (from reference): B,T,M,D,DOUT = 2,10000,100000,128,128
#define BB    2
#define TT    10000
#define MM    100000
#define DD    128
#define DOUTN 128
#define NROWS (BB * TT * 2)     // 40000 rows of X / y / out
#define NTILES (NROWS / 16)     // 2500 MFMA row-tiles (exact)
#define WPITCH 136              // LDS pitch in shorts: 272 B/row -> 2-way-only bank aliasing

typedef float  f32x4  __attribute__((ext_vector_type(4)));
typedef short  bf16x8 __attribute__((ext_vector_type(8)));

static __device__ __forceinline__ short f2bf(float f) {
    union { float f; unsigned u; } v; v.f = f;
    unsigned r = v.u + 0x7fffu + ((v.u >> 16) & 1u);   // RNE
    return (short)(r >> 16);
}

// ---------------------------------------------------------------------------
// GEMM: y = X * W^T (no bias). Block stages W->bf16 in LDS once; each wave
// computes one 16-row x 128-col tile. 625 blocks x 4 waves = 2500 tiles exact.
// No per-wave global W hoist, no big fp32 live ranges -> no spills.
// ---------------------------------------------------------------------------
__global__ __launch_bounds__(256)
void gemm_y_kernel(const float* __restrict__ X, const float* __restrict__ W,
                   float* __restrict__ y) {
    __shared__ __align__(16) short Wb[DOUTN * WPITCH];   // 34.8 KB

    const int tid = threadIdx.x;
    // ---- stage W (fp32 global) -> bf16 LDS, row n padded to WPITCH ----
    {
        const int n  = tid >> 1;            // output col 0..127
        const int kh = (tid & 1) * 64;      // k half
        const float* wp = W + n * DD + kh;
        short* dst = &Wb[n * WPITCH + kh];
#pragma unroll
        for (int e = 0; e < 8; ++e) {
            float4 a = *(const float4*)(wp + e * 8);
            float4 b = *(const float4*)(wp + e * 8 + 4);
            bf16x8 t;
            t[0] = f2bf(a.x); t[1] = f2bf(a.y); t[2] = f2bf(a.z); t[3] = f2bf(a.w);
            t[4] = f2bf(b.x); t[5] = f2bf(b.y); t[6] = f2bf(b.z); t[7] = f2bf(b.w);
            *(bf16x8*)(dst + e * 8) = t;    // 16B aligned: n*272 + kh*2 + e*16
        }
    }
    __syncthreads();

    const int lane = tid & 63;
    const int wid  = tid >> 6;
    const int l15  = lane & 15;
    const int q    = lane >> 4;             // 0..3
    const int tile = blockIdx.x * 4 + wid;  // 0..2499, always valid

    // ---- B-frags from LDS: frag(ot,s) lane holds n=ot*16+l15, k=s*32+q*8+j ----
    bf16x8 bfrag[8][4];
#pragma unroll
    for (int ot = 0; ot < 8; ++ot)
#pragma unroll
        for (int s = 0; s < 4; ++s)
            bfrag[ot][s] = *(const bf16x8*)&Wb[(ot * 16 + l15) * WPITCH + s * 32 + q * 8];

    // ---- A-frags straight from global: lane holds m=l15, k=s*32+q*8+j ----
    const float* xp = X + (size_t)(tile * 16 + l15) * DD + q * 8;
    bf16x8 afrag[4];
#pragma unroll
    for (int s = 0; s < 4; ++s) {
        float4 a0 = *(const float4*)(xp + s * 32);
        float4 a1 = *(const float4*)(xp + s * 32 + 4);
        bf16x8 t;
        t[0] = f2bf(a0.x); t[1] = f2bf(a0.y); t[2] = f2bf(a0.z); t[3] = f2bf(a0.w);
        t[4] = f2bf(a1.x); t[5] = f2bf(a1.y); t[6] = f2bf(a1.z); t[7] = f2bf(a1.w);
        afrag[s] = t;
    }

    f32x4 acc[8];
#pragma unroll
    for (int ot = 0; ot < 8; ++ot) acc[ot] = (f32x4){0.f, 0.f, 0.f, 0.f};
#pragma unroll
    for (int s = 0; s < 4; ++s)
#pragma unroll
        for (int ot = 0; ot < 8; ++ot)
            acc[ot] = __builtin_amdgcn_mfma_f32_16x16x32_bf16(afrag[s], bfrag[ot][s], acc[ot], 0, 0, 0);

    // ---- D layout: col = ot*16 + l15, row = tile*16 + q*4 + r ----
#pragma unroll
    for (int ot = 0; ot < 8; ++ot) {
        const int col = ot * 16 + l15;
#pragma unroll
        for (int r = 0; r < 4; ++r) {
            const int row = tile * 16 + q * 4 + r;
            y[(size_t)row * DOUTN + col] = acc[ot][r];
        }
    }
}

// ---------------------------------------------------------------------------
// CSR build: cnt -> scan -> fill. cur[] is count, then cursor, then bucket-end.
// ---------------------------------------------------------------------------
__global__ __launch_bounds__(256)
void hist_kernel(const int* __restrict__ edge, int* __restrict__ cnt) {
    const int m = blockIdx.x * 256 + threadIdx.x;
    if (m < MM) atomicAdd(&cnt[edge[m]], 1);   // edge[0][m] = node_in = dest
}

#define SCAN_T 1024
#define SCAN_CH 10    // 1024*10 = 10240 >= TT
__global__ __launch_bounds__(SCAN_T)
void scan_kernel(int* __restrict__ cur) {
    __shared__ int sh[SCAN_T];
    const int tid = threadIdx.x;
    int vals[SCAN_CH];
    int sum = 0;
    const int base_i = tid * SCAN_CH;
#pragma unroll
    for (int j = 0; j < SCAN_CH; ++j) {
        const int i = base_i + j;
        const int v = (i < TT) ? cur[i] : 0;
        vals[j] = v; sum += v;
    }
    sh[tid] = sum;
    __syncthreads();
    for (int off = 1; off < SCAN_T; off <<= 1) {
        const int v = (tid >= off) ? sh[tid - off] : 0;
        __syncthreads();
        sh[tid] += v;
        __syncthreads();
    }
    int run = (tid == 0) ? 0 : sh[tid - 1];
#pragma unroll
    for (int j = 0; j < SCAN_CH; ++j) {
        const int i = base_i + j;
        if (i < TT) { cur[i] = run; run += vals[j]; }   // exclusive prefix = cursor start
    }
}

__global__ __launch_bounds__(256)
void fill_kernel(const int* __restrict__ edge, int* __restrict__ cur,
                 int* __restrict__ bucket) {
    const int m = blockIdx.x * 256 + threadIdx.x;
    if (m < MM) {
        const int p = atomicAdd(&cur[edge[m]], 1);
        bucket[p] = m;
    }
    // after this kernel: cur[t] == end of bucket t (inclusive prefix)
}

// ---------------------------------------------------------------------------
// Gather: out[r,:] = y[r,:] + bias + sum_{m: in_m=t} A[b,m] * y[(b,out_m,c),:]
// One wave per row r = (b*TT + t)*2 + c; lane covers 2 floats (float2).
// ---------------------------------------------------------------------------
__global__ __launch_bounds__(256)
void gather_kernel(const float* __restrict__ y, const int* __restrict__ edge,
                   const float* __restrict__ Am, const int* __restrict__ cur_end,
                   const int* __restrict__ bucket, const float* __restrict__ bias,
                   float* __restrict__ out) {
    const int wid  = threadIdx.x >> 6;
    const int lane = threadIdx.x & 63;
    const int r = blockIdx.x * 4 + wid;
    if (r >= NROWS) return;
    const int c = r & 1;
    const int t = (r >> 1) % TT;
    const int b = r / (2 * TT);

    float2 acc = ((const float2*)(y + (size_t)r * DD))[lane];
    const float2 bs = ((const float2*)bias)[lane];

    const int*   esrc = edge + MM;
    const float* Amb  = Am + b * MM;
    const float* yb   = y + (size_t)b * TT * 2 * DD + (size_t)c * DD;

    const int end   = cur_end[t];
    const int start = (t == 0) ? 0 : cur_end[t - 1];
    for (int e = start; e < end; ++e) {
        const int m    = bucket[e];
        const int nout = esrc[m];              // edge[1][m] = source
        const float w  = Amb[m];
        const float2 v = ((const float2*)(yb + (size_t)nout * 2 * DD))[lane];
        acc.x += w * v.x;
        acc.y += w * v.y;
    }
    float2 o; o.x = acc.x + bs.x; o.y = acc.y + bs.y;
    ((float2*)(out + (size_t)r * DD))[lane] = o;
}

// ---------------------------------------------------------------------------
extern "C" void kernel_launch(void* const* d_in, const int* in_sizes, int n_in,
                              void* d_out, int out_size, void* d_ws, size_t ws_size,
                              hipStream_t stream) {
    const float* x1   = (const float*)d_in[0];   // (B,T,2,D)
    // d_in[1] = x_2nd, unused by the reference
    const int*   edge = (const int*)d_in[2];     // (2,M)
    const float* Am   = (const float*)d_in[3];   // (B,1,M)
    const float* W    = (const float*)d_in[4];   // (DOUT,D)
    const float* bias = (const float*)d_in[5];   // (DOUT,)
    float* out = (float*)d_out;                  // (B,T,2,DOUT)

    // Workspace layout
    float* y      = (float*)d_ws;                          // NROWS*128 fp32 = 20.48 MB
    int*   cur    = (int*)d_ws + (size_t)NROWS * DOUTN;    // TT ints (count->cursor->end)
    int*   bucket = cur + TT;                              // MM ints

    hipMemsetAsync(cur, 0, TT * sizeof(int), stream);
    hist_kernel<<<(MM + 255) / 256, 256, 0, stream>>>(edge, cur);
    scan_kernel<<<1, SCAN_T, 0, stream>>>(cur);
    fill_kernel<<<(MM + 255) / 256, 256, 0, stream>>>(edge, cur, bucket);

    gemm_y_kernel<<<NTILES / 4, 256, 0, stream>>>(x1, W, y);

    gather_kernel<<<(NROWS + 3) / 4, 256, 0, stream>>>(y, edge, Am, cur, bucket, bias, out);
}

// Round 4
// 524.112 us; speedup vs baseline: 2.1722x; 1.0481x over previous
//
#include <hip/hip_runtime.h>
#include <hip/hip_bf16.h>

// Problem constants (from reference): B,T,M,D,DOUT = 2,10000,100000,128,128
#define BB    2
#define TT    10000
#define MM    100000
#define DD    128
#define DOUTN 128
#define NROWS (BB * TT * 2)     // 40000 rows of X / y / out
#define NTILES (NROWS / 16)     // 2500 MFMA row-tiles (exact)
#define WPITCH 136              // LDS pitch in shorts: 272 B/row -> 2-way-only bank aliasing

typedef float  f32x4  __attribute__((ext_vector_type(4)));
typedef short  bf16x8 __attribute__((ext_vector_type(8)));

static __device__ __forceinline__ short f2bf(float f) {
    union { float f; unsigned u; } v; v.f = f;
    unsigned r = v.u + 0x7fffu + ((v.u >> 16) & 1u);   // RNE
    return (short)(r >> 16);
}

// ---------------------------------------------------------------------------
// GEMM: y = X * W^T (no bias). Block stages W->bf16 in LDS once; each wave
// computes one 16-row x 128-col tile. 625 blocks x 4 waves = 2500 tiles exact.
// ---------------------------------------------------------------------------
__global__ __launch_bounds__(256)
void gemm_y_kernel(const float* __restrict__ X, const float* __restrict__ W,
                   float* __restrict__ y) {
    __shared__ __align__(16) short Wb[DOUTN * WPITCH];   // 34.8 KB

    const int tid = threadIdx.x;
    {
        const int n  = tid >> 1;            // output col 0..127
        const int kh = (tid & 1) * 64;      // k half
        const float* wp = W + n * DD + kh;
        short* dst = &Wb[n * WPITCH + kh];
#pragma unroll
        for (int e = 0; e < 8; ++e) {
            float4 a = *(const float4*)(wp + e * 8);
            float4 b = *(const float4*)(wp + e * 8 + 4);
            bf16x8 t;
            t[0] = f2bf(a.x); t[1] = f2bf(a.y); t[2] = f2bf(a.z); t[3] = f2bf(a.w);
            t[4] = f2bf(b.x); t[5] = f2bf(b.y); t[6] = f2bf(b.z); t[7] = f2bf(b.w);
            *(bf16x8*)(dst + e * 8) = t;
        }
    }
    __syncthreads();

    const int lane = tid & 63;
    const int wid  = tid >> 6;
    const int l15  = lane & 15;
    const int q    = lane >> 4;             // 0..3
    const int tile = blockIdx.x * 4 + wid;  // 0..2499, always valid

    bf16x8 bfrag[8][4];
#pragma unroll
    for (int ot = 0; ot < 8; ++ot)
#pragma unroll
        for (int s = 0; s < 4; ++s)
            bfrag[ot][s] = *(const bf16x8*)&Wb[(ot * 16 + l15) * WPITCH + s * 32 + q * 8];

    const float* xp = X + (size_t)(tile * 16 + l15) * DD + q * 8;
    bf16x8 afrag[4];
#pragma unroll
    for (int s = 0; s < 4; ++s) {
        float4 a0 = *(const float4*)(xp + s * 32);
        float4 a1 = *(const float4*)(xp + s * 32 + 4);
        bf16x8 t;
        t[0] = f2bf(a0.x); t[1] = f2bf(a0.y); t[2] = f2bf(a0.z); t[3] = f2bf(a0.w);
        t[4] = f2bf(a1.x); t[5] = f2bf(a1.y); t[6] = f2bf(a1.z); t[7] = f2bf(a1.w);
        afrag[s] = t;
    }

    f32x4 acc[8];
#pragma unroll
    for (int ot = 0; ot < 8; ++ot) acc[ot] = (f32x4){0.f, 0.f, 0.f, 0.f};
#pragma unroll
    for (int s = 0; s < 4; ++s)
#pragma unroll
        for (int ot = 0; ot < 8; ++ot)
            acc[ot] = __builtin_amdgcn_mfma_f32_16x16x32_bf16(afrag[s], bfrag[ot][s], acc[ot], 0, 0, 0);

#pragma unroll
    for (int ot = 0; ot < 8; ++ot) {
        const int col = ot * 16 + l15;
#pragma unroll
        for (int r = 0; r < 4; ++r) {
            const int row = tile * 16 + q * 4 + r;
            y[(size_t)row * DOUTN + col] = acc[ot][r];
        }
    }
}

// ---------------------------------------------------------------------------
// CSR build: cnt -> scan -> fill.
// ---------------------------------------------------------------------------
__global__ __launch_bounds__(256)
void hist_kernel(const int* __restrict__ edge, int* __restrict__ cnt) {
    const int m = blockIdx.x * 256 + threadIdx.x;
    if (m < MM) atomicAdd(&cnt[edge[m]], 1);   // edge[0][m] = node_in = dest
}

#define SCAN_T 1024
#define SCAN_CH 10    // 1024*10 = 10240 >= TT
__global__ __launch_bounds__(SCAN_T)
void scan_kernel(int* __restrict__ cur) {
    __shared__ int sh[SCAN_T];
    const int tid = threadIdx.x;
    int vals[SCAN_CH];
    int sum = 0;
    const int base_i = tid * SCAN_CH;
#pragma unroll
    for (int j = 0; j < SCAN_CH; ++j) {
        const int i = base_i + j;
        const int v = (i < TT) ? cur[i] : 0;
        vals[j] = v; sum += v;
    }
    sh[tid] = sum;
    __syncthreads();
    for (int off = 1; off < SCAN_T; off <<= 1) {
        const int v = (tid >= off) ? sh[tid - off] : 0;
        __syncthreads();
        sh[tid] += v;
        __syncthreads();
    }
    int run = (tid == 0) ? 0 : sh[tid - 1];
#pragma unroll
    for (int j = 0; j < SCAN_CH; ++j) {
        const int i = base_i + j;
        if (i < TT) { cur[i] = run; run += vals[j]; }
    }
}

__global__ __launch_bounds__(256)
void fill_kernel(const int* __restrict__ edge, int* __restrict__ cur,
                 int* __restrict__ bucket) {
    const int m = blockIdx.x * 256 + threadIdx.x;
    if (m < MM) {
        const int p = atomicAdd(&cur[edge[m]], 1);
        bucket[p] = m;
    }
    // after this kernel: cur[t] == end of bucket t (inclusive prefix)
}

// ---------------------------------------------------------------------------
// Gather: one WAVE per node t handles all 4 (b,c) output rows.
//   out[(b,t,c),:] = y[(b,t,c),:] + bias + sum_{m: in_m=t} Am[b,m]*y[(b,out_m,c),:]
// Metadata for the whole bucket is loaded lane-parallel, then broadcast with
// v_readlane -> the per-edge loop has ZERO dependent scalar loads; the 4 y-row
// loads per edge are independent and pipeline across iterations.
// ---------------------------------------------------------------------------
__global__ __launch_bounds__(256)
void gather_kernel(const float* __restrict__ y, const int* __restrict__ edge,
                   const float* __restrict__ Am, const int* __restrict__ cur_end,
                   const int* __restrict__ bucket, const float* __restrict__ bias,
                   float* __restrict__ out) {
    const int lane = threadIdx.x & 63;
    const int t    = blockIdx.x * 4 + (threadIdx.x >> 6);   // 2500*4 = 10000 exact

    const int end   = cur_end[t];
    const int start = (t == 0) ? 0 : cur_end[t - 1];

    // accumulators: a[b][c] as float2 per lane; init with own row of y
    const float* yb0 = y + (size_t)t * 256;            // (b0,t,c0) row; c1 at +128
    const float* yb1 = y + (size_t)(TT + t) * 256;     // (b1,t,c0) row; c1 at +128
    float2 a00 = ((const float2*)yb0)[lane];
    float2 a01 = ((const float2*)(yb0 + 128))[lane];
    float2 a10 = ((const float2*)yb1)[lane];
    float2 a11 = ((const float2*)(yb1 + 128))[lane];

    const int* esrc = edge + MM;

    for (int base = start; base < end; base += 64) {
        const int n = min(end - base, 64);
        int nout = 0; float w0 = 0.f, w1 = 0.f;
        if (lane < n) {
            const int m = bucket[base + lane];
            nout = esrc[m];
            w0   = Am[m];          // b = 0
            w1   = Am[MM + m];     // b = 1
        }
        for (int e = 0; e < n; ++e) {
            const int   no  = __builtin_amdgcn_readlane(nout, e);
            const float ww0 = __uint_as_float(__builtin_amdgcn_readlane(__float_as_uint(w0), e));
            const float ww1 = __uint_as_float(__builtin_amdgcn_readlane(__float_as_uint(w1), e));
            const float* p0 = y + (size_t)no * 256;            // (b0,no,c0)
            const float* p1 = y + (size_t)(TT + no) * 256;     // (b1,no,c0)
            const float2 v00 = ((const float2*)p0)[lane];
            const float2 v01 = ((const float2*)(p0 + 128))[lane];
            const float2 v10 = ((const float2*)p1)[lane];
            const float2 v11 = ((const float2*)(p1 + 128))[lane];
            a00.x += ww0 * v00.x; a00.y += ww0 * v00.y;
            a01.x += ww0 * v01.x; a01.y += ww0 * v01.y;
            a10.x += ww1 * v10.x; a10.y += ww1 * v10.y;
            a11.x += ww1 * v11.x; a11.y += ww1 * v11.y;
        }
    }

    const float2 bs = ((const float2*)bias)[lane];
    float* o0 = out + (size_t)t * 256;
    float* o1 = out + (size_t)(TT + t) * 256;
    float2 r;
    r.x = a00.x + bs.x; r.y = a00.y + bs.y; ((float2*)o0)[lane]         = r;
    r.x = a01.x + bs.x; r.y = a01.y + bs.y; ((float2*)(o0 + 128))[lane] = r;
    r.x = a10.x + bs.x; r.y = a10.y + bs.y; ((float2*)o1)[lane]         = r;
    r.x = a11.x + bs.x; r.y = a11.y + bs.y; ((float2*)(o1 + 128))[lane] = r;
}

// ---------------------------------------------------------------------------
extern "C" void kernel_launch(void* const* d_in, const int* in_sizes, int n_in,
                              void* d_out, int out_size, void* d_ws, size_t ws_size,
                              hipStream_t stream) {
    const float* x1   = (const float*)d_in[0];   // (B,T,2,D)
    // d_in[1] = x_2nd, unused by the reference
    const int*   edge = (const int*)d_in[2];     // (2,M)
    const float* Am   = (const float*)d_in[3];   // (B,1,M)
    const float* W    = (const float*)d_in[4];   // (DOUT,D)
    const float* bias = (const float*)d_in[5];   // (DOUT,)
    float* out = (float*)d_out;                  // (B,T,2,DOUT)

    // Workspace layout
    float* y      = (float*)d_ws;                          // NROWS*128 fp32 = 20.48 MB
    int*   cur    = (int*)d_ws + (size_t)NROWS * DOUTN;    // TT ints
    int*   bucket = cur + TT;                              // MM ints

    hipMemsetAsync(cur, 0, TT * sizeof(int), stream);
    hist_kernel<<<(MM + 255) / 256, 256, 0, stream>>>(edge, cur);
    scan_kernel<<<1, SCAN_T, 0, stream>>>(cur);
    fill_kernel<<<(MM + 255) / 256, 256, 0, stream>>>(edge, cur, bucket);

    gemm_y_kernel<<<NTILES / 4, 256, 0, stream>>>(x1, W, y);

    gather_kernel<<<TT / 4, 256, 0, stream>>>(y, edge, Am, cur, bucket, bias, out);
}